// Round 13
// baseline (117.790 us; speedup 1.0000x reference)
//
#include <hip/hip_runtime.h>
#include <hip/hip_bf16.h>
#include <math.h>

#define BB 32
#define SS 32
#define DD 768
#define FFD 3072
#define EE 8
#define KK 2
#define NPAIR 64
#define MAXT 15   // BM=256 = 8-pair tiles: sum ceil(cnt/8) <= 8 + 7 = 15

typedef __attribute__((ext_vector_type(8))) short short8;
typedef __attribute__((ext_vector_type(4))) float f32x4;
typedef __attribute__((ext_vector_type(4))) unsigned short us4;
typedef __attribute__((ext_vector_type(8))) unsigned short us8;

// ws layout:
//   ints [0..63] gates, [64..127] spair, [128..142] te_e, [152..166] te_s,
//        [176..190] te_np, [200..263] slot_of_pair   (ends @ byte 1056)
//   H    bf16 [2048][3072]    @ 4096        (12.58 MB)
//   xbf  bf16 [1024][768]     @ XBF_OFF     (1.57 MB)  -- dead after up_gemm
//   part bf16 [4][2048][768]  @ PART_OFF = XBF_OFF (overlay)   (12.58 MB)
//   end = 25,169,920 B (R12-proven resident: MODE 0 ran there)

#define H_OFF    4096
#define XBF_OFF  (H_OFF + 12582912)
#define PART_OFF XBF_OFF
#define PZ       (2048 * 768)
#define WS_MAIN  ((size_t)PART_OFF + 4ull * PZ * 2ull)

__device__ __forceinline__ unsigned short f2bf(float f) {
    __hip_bfloat16 h = __float2bfloat16(f);
    return __builtin_bit_cast(unsigned short, h);
}
__device__ __forceinline__ float bf2f(unsigned short u) {
    __hip_bfloat16 h = __builtin_bit_cast(__hip_bfloat16, u);
    return __bfloat162float(h);
}

// 64B logical rows packed in pairs into 128B physical rows, XOR-swizzled
// (bits 4-6 of the 7-bit in-row offset XOR physical-row&7). byte < 64.
__device__ __forceinline__ int off64(int row, int byte) {
    return (row >> 1) * 128 + ((((row & 1) << 6) | byte) ^ (((row >> 1) & 7) << 4));
}

// lgkm-only barrier: orders LDS producer->consumer; global-load prefetch
// stays in flight across it (compiler adds precise vmcnt at reg-use sites).
__device__ __forceinline__ void phase_barrier() {
    __builtin_amdgcn_sched_barrier(0);
    asm volatile("s_waitcnt lgkmcnt(0)" ::: "memory");
    __builtin_amdgcn_s_barrier();
    __builtin_amdgcn_sched_barrier(0);
}

// ---------------------------------------------------------------------------
__global__ __launch_bounds__(256) void gate_kernel(
    const float* __restrict__ x, const float* __restrict__ Wg,
    const float* __restrict__ bg, float* __restrict__ out,
    int* __restrict__ gates)
{
    int b = blockIdx.x;
    int tid = threadIdx.x;

    float acc[EE];
#pragma unroll
    for (int e = 0; e < EE; ++e) acc[e] = 0.f;

    for (int d = tid; d < DD; d += 256) {
        float xs = 0.f;
        const float* xp = x + (size_t)b * SS * DD + d;
#pragma unroll
        for (int s = 0; s < SS; ++s) xs += xp[(size_t)s * DD];
#pragma unroll
        for (int e = 0; e < EE; ++e) acc[e] += xs * Wg[d * EE + e];
    }

    __shared__ float red[EE][256];
#pragma unroll
    for (int e = 0; e < EE; ++e) red[e][tid] = acc[e];
    __syncthreads();
    for (int offr = 128; offr > 0; offr >>= 1) {
        if (tid < offr) {
#pragma unroll
            for (int e = 0; e < EE; ++e) red[e][tid] += red[e][tid + offr];
        }
        __syncthreads();
    }

    if (tid == 0) {
        float lg[EE], p[EE];
        float m = -1e30f;
#pragma unroll
        for (int e = 0; e < EE; ++e) {
            lg[e] = red[e][0] / (float)SS + bg[e];
            m = fmaxf(m, lg[e]);
        }
        float sum = 0.f;
#pragma unroll
        for (int e = 0; e < EE; ++e) { p[e] = expf(lg[e] - m); sum += p[e]; }
        float inv = 1.f / sum;
#pragma unroll
        for (int e = 0; e < EE; ++e) p[e] *= inv;

        int i1 = 0;
        for (int e = 1; e < EE; ++e) if (p[e] > p[i1]) i1 = e;
        int i2 = (i1 == 0) ? 1 : 0;
        for (int e = 0; e < EE; ++e) if (e != i1 && p[e] > p[i2]) i2 = e;

        float* prob_out = out + (size_t)BB * SS * DD;
        float* gate_out = prob_out + BB * KK;
        prob_out[b * KK + 0] = p[i1];
        prob_out[b * KK + 1] = p[i2];
        gate_out[b * KK + 0] = (float)i1;
        gate_out[b * KK + 1] = (float)i2;
        gates[b * KK + 0] = i1;
        gates[b * KK + 1] = i2;
    }
}

// ---------------------------------------------------------------------------
// schedule: group pairs by expert, tiles of 8 pairs (BM=256 rows)
__global__ void sched_kernel(int* __restrict__ wsi)
{
    if (threadIdx.x != 0 || blockIdx.x != 0) return;
    const int* gates = wsi;
    int* spair = wsi + 64;
    int* te_e = wsi + 128;
    int* te_s = wsi + 152;
    int* te_n = wsi + 176;
    int* slotof = wsi + 200;

    int cnt[EE];
    for (int e = 0; e < EE; ++e) cnt[e] = 0;
    for (int p = 0; p < NPAIR; ++p) cnt[gates[p]]++;
    int start[EE + 1];
    start[0] = 0;
    for (int e = 0; e < EE; ++e) start[e + 1] = start[e] + cnt[e];
    int fill[EE];
    for (int e = 0; e < EE; ++e) fill[e] = start[e];
    for (int p = 0; p < NPAIR; ++p) {
        int s = fill[gates[p]]++;
        spair[s] = p;
        slotof[p] = s;
    }

    int t = 0;
    for (int e = 0; e < EE; ++e) {
        for (int o = 0; o < cnt[e]; o += 8) {
            te_e[t] = e;
            te_s[t] = start[e] + o;
            te_n[t] = (cnt[e] - o) < 8 ? (cnt[e] - o) : 8;
            ++t;
        }
    }
    for (; t < MAXT; ++t) te_n[t] = 0;
}

// ---------------------------------------------------------------------------
// x -> bf16 pack (once): 786432 elems, 8/thread
__global__ __launch_bounds__(256) void pack_x(
    const float* __restrict__ x, unsigned short* __restrict__ xbf)
{
    int i = blockIdx.x * 256 + threadIdx.x;   // 384 blocks
    const float4* src = (const float4*)(x + (size_t)i * 8);
    float4 v0 = src[0], v1 = src[1];
    us8 u;
    u[0] = f2bf(v0.x); u[1] = f2bf(v0.y); u[2] = f2bf(v0.z); u[3] = f2bf(v0.w);
    u[4] = f2bf(v1.x); u[5] = f2bf(v1.y); u[6] = f2bf(v1.z); u[7] = f2bf(v1.w);
    *(us8*)(xbf + (size_t)i * 8) = u;
}

// ---------------------------------------------------------------------------
// Fallback init: out = bias sums (down<1> atomics add on top)
__global__ __launch_bounds__(256) void init_kernel(
    const int* __restrict__ gates, const float* __restrict__ b2,
    float* __restrict__ out)
{
    int idx = blockIdx.x * 256 + threadIdx.x;
    if (idx >= BB * SS * DD) return;
    int b = idx / (SS * DD);
    int d = idx % DD;
    int e0 = gates[b * KK + 0];
    int e1 = gates[b * KK + 1];
    out[idx] = b2[e0 * DD + d] + b2[e1 * DD + d];
}

// ---------------------------------------------------------------------------
// Up GEMM: H = gelu(xbf @ W1[e] + b1); BM=256 BN=128 BK=32, 1024 threads
// (16 waves, 4M x 4N, wave-tile 64x32, acc 32 VGPR). A: 1 us8/thread/set;
// B: 4 fp32/thread/set (dual sets, issue-before-store). LDS dbuf 48KB
// (A 16K + B 8K per buf, 64B-logical-row swizzle). 24 phases.
// grid (24 nt, MAXT).
__global__ __launch_bounds__(1024, 4) void up_gemm(
    const unsigned short* __restrict__ xbf, const float* __restrict__ W1,
    const float* __restrict__ b1, const int* __restrict__ wsi,
    unsigned short* __restrict__ H)
{
    int tile = blockIdx.y;
    int np = wsi[176 + tile];
    if (np == 0) return;
    int e = wsi[128 + tile];
    int slot0 = wsi[152 + tile];
    int nt = blockIdx.x;
    int tid = threadIdx.x;
    int wid = tid >> 6, lane = tid & 63;
    int wm = wid >> 2, wn = wid & 3;     // 4 x 4 wave grid

    __shared__ char lds[49152];   // per buf: A 16KB + B 8KB

    // A: 256 rows x 4 chunks(8 bf16) = 1024 chunks, 1/thread
    int arow = tid >> 2, ach = tid & 3;
    {
    }
    int lp = arow >> 5;
    int lpc = lp < np ? lp : np - 1;
    int apair = wsi[64 + slot0 + lpc];
    const unsigned short* asrc =
        xbf + ((size_t)((apair >> 1) * SS + (arow & 31))) * DD + ach * 8;
    int aoff = off64(arow, ach * 16);

    // B: [k][n] source; LDS [n][k] 64B rows. thread: n = tid&127, kq = tid>>7
    int n = tid & 127, kq = tid >> 7;    // kq in 0..7, k-rows kq*4 + j
    const float* bsrc = W1 + ((size_t)e * DD + kq * 4) * FFD + nt * 128 + n;
    int boff = off64(n, kq * 8);

    f32x4 acc[4][2];
#pragma unroll
    for (int i = 0; i < 4; ++i)
#pragma unroll
        for (int j = 0; j < 2; ++j) acc[i][j] = (f32x4)0.f;

    us8 a0, a1;
    float b0r[4], b1r[4];

    auto issueA = [&](us8& a, int k0) { a = *(const us8*)(asrc + k0); };
    auto issueB = [&](float (&br)[4], int k0) {
        const float* wp = bsrc + (size_t)k0 * FFD;
#pragma unroll
        for (int j = 0; j < 4; ++j) br[j] = wp[(size_t)j * FFD];
    };
    auto storeA = [&](int p, const us8& a) {
        *(us8*)(lds + p * 24576 + aoff) = a;
    };
    auto storeB = [&](int p, const float (&br)[4]) {
        us4 u;
#pragma unroll
        for (int j = 0; j < 4; ++j) u[j] = f2bf(br[j]);
        *(us4*)(lds + p * 24576 + 16384 + boff) = u;
    };
    auto compute = [&](int p) {
        char* Al = lds + p * 24576;
        char* Bl = Al + 16384;
        int kb = (lane >> 4) * 16;
        short8 af[4], bf[2];
#pragma unroll
        for (int mf = 0; mf < 4; ++mf)
            af[mf] = *(short8*)(Al + off64(wm * 64 + mf * 16 + (lane & 15), kb));
#pragma unroll
        for (int nf = 0; nf < 2; ++nf)
            bf[nf] = *(short8*)(Bl + off64(wn * 32 + nf * 16 + (lane & 15), kb));
#pragma unroll
        for (int mf = 0; mf < 4; ++mf)
#pragma unroll
            for (int nf = 0; nf < 2; ++nf)
                acc[mf][nf] = __builtin_amdgcn_mfma_f32_16x16x32_bf16(
                    af[mf], bf[nf], acc[mf][nf], 0, 0, 0);
    };

    const int steps = 24;   // DD/32
    issueA(a0, 0);  issueB(b0r, 0);
    issueA(a1, 32); issueB(b1r, 32);
    storeA(0, a0);  storeB(0, b0r);
    phase_barrier();

    for (int s = 0; s < steps; s += 2) {
        compute(0);
        if (s + 2 < steps) { issueA(a0, (s + 2) * 32); issueB(b0r, (s + 2) * 32); }
        storeA(1, a1); storeB(1, b1r);
        phase_barrier();
        compute(1);
        if (s + 3 < steps) { issueA(a1, (s + 3) * 32); issueB(b1r, (s + 3) * 32); }
        if (s + 2 < steps) { storeA(0, a0); storeB(0, b0r); }
        phase_barrier();
    }

    // epilogue: bias + exact gelu -> bf16 H (grouped slot rows)
    float bias[2];
#pragma unroll
    for (int nf = 0; nf < 2; ++nf)
        bias[nf] = b1[e * FFD + nt * 128 + wn * 32 + nf * 16 + (lane & 15)];
#pragma unroll
    for (int mf = 0; mf < 4; ++mf) {
#pragma unroll
        for (int i = 0; i < 4; ++i) {
            int row = wm * 64 + mf * 16 + (lane >> 4) * 4 + i;
            if ((row >> 5) >= np) continue;
            size_t srow = (size_t)(slot0 * 32 + row);
#pragma unroll
            for (int nf = 0; nf < 2; ++nf) {
                int f = nt * 128 + wn * 32 + nf * 16 + (lane & 15);
                float h = acc[mf][nf][i] + bias[nf];
                float g = 0.5f * h * (1.0f + erff(h * 0.70710678118654752f));
                H[srow * FFD + f] = f2bf(g);
            }
        }
    }
}

// ---------------------------------------------------------------------------
// Down GEMM: same structure; BM=256 BN=128 BK=32, z=4 K-split (24 phases).
// MODE 0: bf16 partials to part[z]; MODE 1: atomic fallback.
// grid (6 nt, MAXT, 4).
template<int MODE>
__global__ __launch_bounds__(1024, 4) void down_gemm(
    const unsigned short* __restrict__ H, const float* __restrict__ W2,
    const int* __restrict__ wsi, unsigned short* __restrict__ part,
    float* __restrict__ out)
{
    int tile = blockIdx.y;
    int np = wsi[176 + tile];
    if (np == 0) return;
    int e = wsi[128 + tile];
    int slot0 = wsi[152 + tile];
    int nt = blockIdx.x;
    int z = blockIdx.z;
    int zb = z * (FFD / 4);
    int tid = threadIdx.x;
    int wid = tid >> 6, lane = tid & 63;
    int wm = wid >> 2, wn = wid & 3;

    __shared__ char lds[49152];

    int arow = tid >> 2, ach = tid & 3;
    int rc = arow < np * 32 ? arow : np * 32 - 1;
    const unsigned short* asrc =
        H + (size_t)(slot0 * 32 + rc) * FFD + zb + ach * 8;
    int aoff = off64(arow, ach * 16);

    int n = tid & 127, kq = tid >> 7;
    const float* bsrc = W2 + ((size_t)e * FFD + zb + kq * 4) * DD + nt * 128 + n;
    int boff = off64(n, kq * 8);

    f32x4 acc[4][2];
#pragma unroll
    for (int i = 0; i < 4; ++i)
#pragma unroll
        for (int j = 0; j < 2; ++j) acc[i][j] = (f32x4)0.f;

    us8 a0, a1;
    float b0r[4], b1r[4];

    auto issueA = [&](us8& a, int k0) { a = *(const us8*)(asrc + k0); };
    auto issueB = [&](float (&br)[4], int k0) {
        const float* wp = bsrc + (size_t)k0 * DD;
#pragma unroll
        for (int j = 0; j < 4; ++j) br[j] = wp[(size_t)j * DD];
    };
    auto storeA = [&](int p, const us8& a) {
        *(us8*)(lds + p * 24576 + aoff) = a;
    };
    auto storeB = [&](int p, const float (&br)[4]) {
        us4 u;
#pragma unroll
        for (int j = 0; j < 4; ++j) u[j] = f2bf(br[j]);
        *(us4*)(lds + p * 24576 + 16384 + boff) = u;
    };
    auto compute = [&](int p) {
        char* Al = lds + p * 24576;
        char* Bl = Al + 16384;
        int kb = (lane >> 4) * 16;
        short8 af[4], bf[2];
#pragma unroll
        for (int mf = 0; mf < 4; ++mf)
            af[mf] = *(short8*)(Al + off64(wm * 64 + mf * 16 + (lane & 15), kb));
#pragma unroll
        for (int nf = 0; nf < 2; ++nf)
            bf[nf] = *(short8*)(Bl + off64(wn * 32 + nf * 16 + (lane & 15), kb));
#pragma unroll
        for (int mf = 0; mf < 4; ++mf)
#pragma unroll
            for (int nf = 0; nf < 2; ++nf)
                acc[mf][nf] = __builtin_amdgcn_mfma_f32_16x16x32_bf16(
                    af[mf], bf[nf], acc[mf][nf], 0, 0, 0);
    };

    const int steps = 24;   // (FFD/4)/32
    issueA(a0, 0);  issueB(b0r, 0);
    issueA(a1, 32); issueB(b1r, 32);
    storeA(0, a0);  storeB(0, b0r);
    phase_barrier();

    for (int s = 0; s < steps; s += 2) {
        compute(0);
        if (s + 2 < steps) { issueA(a0, (s + 2) * 32); issueB(b0r, (s + 2) * 32); }
        storeA(1, a1); storeB(1, b1r);
        phase_barrier();
        compute(1);
        if (s + 3 < steps) { issueA(a1, (s + 3) * 32); issueB(b1r, (s + 3) * 32); }
        if (s + 2 < steps) { storeA(0, a0); storeB(0, b0r); }
        phase_barrier();
    }

    // epilogue
#pragma unroll
    for (int mf = 0; mf < 4; ++mf) {
#pragma unroll
        for (int i = 0; i < 4; ++i) {
            int row = wm * 64 + mf * 16 + (lane >> 4) * 4 + i;
            int lp = row >> 5;
            if (lp >= np) continue;
            int col = nt * 128 + wn * 32 + (lane & 15);
            if (MODE == 0) {
                size_t srow = (size_t)(slot0 * 32 + row);
                unsigned short* pp = part + (size_t)z * PZ + srow * DD + col;
#pragma unroll
                for (int nf = 0; nf < 2; ++nf) pp[nf * 16] = f2bf(acc[mf][nf][i]);
            } else {
                int pair = wsi[64 + slot0 + lp];
                int b = pair >> 1;
                int sI = row & 31;
                float* op = out + ((size_t)(b * SS + sI)) * DD + col;
#pragma unroll
                for (int nf = 0; nf < 2; ++nf)
                    atomicAdd(op + nf * 16, acc[mf][nf][i]);
            }
        }
    }
}

// ---------------------------------------------------------------------------
// Reduce: out[b,s,d0..d0+7] = sum_{k,z} part[z][slot(b,k)*32+s][d] + biases
__global__ __launch_bounds__(512) void reduce_kernel(
    const unsigned short* __restrict__ part, const int* __restrict__ wsi,
    const float* __restrict__ b2, float* __restrict__ out)
{
    int i8 = blockIdx.x * 512 + threadIdx.x;    // 98304 threads, 8 elems each
    int flat = i8 * 8;
    int b = flat / (SS * DD);
    int r = flat - b * (SS * DD);
    int s = r / DD;
    int d = r - s * DD;

    int e0 = wsi[b * KK + 0];
    int e1 = wsi[b * KK + 1];
    int sl0 = wsi[200 + b * KK + 0];
    int sl1 = wsi[200 + b * KK + 1];
    size_t r0 = (size_t)(sl0 * 32 + s) * DD + d;
    size_t r1 = (size_t)(sl1 * 32 + s) * DD + d;

    const float* bb0 = b2 + e0 * DD + d;
    const float* bb1 = b2 + e1 * DD + d;

    float v[8];
#pragma unroll
    for (int j = 0; j < 8; ++j) v[j] = bb0[j] + bb1[j];
#pragma unroll
    for (int z = 0; z < 4; ++z) {
        us8 p0 = *(const us8*)(part + (size_t)z * PZ + r0);
        us8 p1 = *(const us8*)(part + (size_t)z * PZ + r1);
#pragma unroll
        for (int j = 0; j < 8; ++j) v[j] += bf2f(p0[j]) + bf2f(p1[j]);
    }
    float4* op = (float4*)(out + flat);
    op[0] = make_float4(v[0], v[1], v[2], v[3]);
    op[1] = make_float4(v[4], v[5], v[6], v[7]);
}

// ---------------------------------------------------------------------------
extern "C" void kernel_launch(void* const* d_in, const int* in_sizes, int n_in,
                              void* d_out, int out_size, void* d_ws, size_t ws_size,
                              hipStream_t stream) {
    const float* x  = (const float*)d_in[0];
    const float* Wg = (const float*)d_in[2];
    const float* bg = (const float*)d_in[3];
    const float* W1 = (const float*)d_in[4];
    const float* b1 = (const float*)d_in[5];
    const float* W2 = (const float*)d_in[6];
    const float* b2 = (const float*)d_in[7];
    float* out = (float*)d_out;

    int* wsi = (int*)d_ws;
    unsigned short* H    = (unsigned short*)((char*)d_ws + H_OFF);
    unsigned short* xbf  = (unsigned short*)((char*)d_ws + XBF_OFF);
    unsigned short* part = (unsigned short*)((char*)d_ws + PART_OFF);
    // xbf/part overlay safe: pack_x -> up_gemm (reads xbf) -> down_gemm
    // (writes part) are stream-ordered.

    gate_kernel<<<BB, 256, 0, stream>>>(x, Wg, bg, out, wsi);
    sched_kernel<<<1, 64, 0, stream>>>(wsi);
    pack_x<<<(BB * SS * DD) / (256 * 8), 256, 0, stream>>>(x, xbf);
    up_gemm<<<dim3(FFD / 128, MAXT), 1024, 0, stream>>>(xbf, W1, b1, wsi, H);

    if (ws_size >= WS_MAIN) {
        down_gemm<0><<<dim3(DD / 128, MAXT, 4), 1024, 0, stream>>>(
            H, W2, wsi, part, out);
        reduce_kernel<<<(BB * SS * DD) / (512 * 8), 512, 0, stream>>>(
            part, wsi, b2, out);
    } else {
        init_kernel<<<(BB * SS * DD + 255) / 256, 256, 0, stream>>>(wsi, b2, out);
        down_gemm<1><<<dim3(DD / 128, MAXT, 4), 1024, 0, stream>>>(
            H, W2, wsi, part, out);
    }
}

// Round 14
// 111.569 us; speedup vs baseline: 1.0558x; 1.0558x over previous
//
#include <hip/hip_runtime.h>
#include <hip/hip_bf16.h>
#include <math.h>

#define BB 32
#define SS 32
#define DD 768
#define FFD 3072
#define EE 8
#define KK 2
#define NPAIR 64
#define MAXT 22   // tiles of 4 pairs (BM=128)

typedef __attribute__((ext_vector_type(8))) short short8;
typedef __attribute__((ext_vector_type(4))) float f32x4;
typedef __attribute__((ext_vector_type(8))) unsigned short us8;

// ws layout:
//   ints [0..63] gates, [64..127] spair, [128..149] te_e, [152..173] te_s,
//        [176..197] te_np, [200..263] slot_of_pair   (ends @ byte 1056)
//   H    bf16 [2048][3072]    @ 4096        (12.58 MB)
//   xbf  bf16 [1024][768]     @ XBF_OFF     (1.57 MB)  -- dead after up_gemm
//   part bf16 [2][2048][768]  @ PART_OFF = XBF_OFF (overlay)   (6.29 MB)
//   end ~18.9 MB  (< R7-proven 25.2 MB resident bound)

#define H_OFF    4096
#define XBF_OFF  (H_OFF + 12582912)
#define PART_OFF XBF_OFF
#define PZ       (2048 * 768)
#define WS_MAIN  ((size_t)PART_OFF + 2ull * PZ * 2ull)

__device__ __forceinline__ unsigned short f2bf(float f) {
    __hip_bfloat16 h = __float2bfloat16(f);
    return __builtin_bit_cast(unsigned short, h);
}
__device__ __forceinline__ float bf2f(unsigned short u) {
    __hip_bfloat16 h = __builtin_bit_cast(__hip_bfloat16, u);
    return __bfloat162float(h);
}

// proven swizzle: 128B rows, XOR bits 4-6 with row&7
__device__ __forceinline__ int lds_off(int row, int byte_in_row) {
    return row * 128 + (byte_in_row ^ ((row & 7) << 4));
}

// lgkm-only barrier (R8/R9-proven correct): orders LDS write->read across
// waves WITHOUT draining vmcnt, so global-load prefetch issued this phase
// stays in flight; compiler adds per-register vmcnt waits at use sites.
__device__ __forceinline__ void phase_barrier() {
    __builtin_amdgcn_sched_barrier(0);
    asm volatile("s_waitcnt lgkmcnt(0)" ::: "memory");
    __builtin_amdgcn_s_barrier();
    __builtin_amdgcn_sched_barrier(0);
}

// ---------------------------------------------------------------------------
__global__ __launch_bounds__(256) void gate_kernel(
    const float* __restrict__ x, const float* __restrict__ Wg,
    const float* __restrict__ bg, float* __restrict__ out,
    int* __restrict__ gates)
{
    int b = blockIdx.x;
    int tid = threadIdx.x;

    float acc[EE];
#pragma unroll
    for (int e = 0; e < EE; ++e) acc[e] = 0.f;

    for (int d = tid; d < DD; d += 256) {
        float xs = 0.f;
        const float* xp = x + (size_t)b * SS * DD + d;
#pragma unroll
        for (int s = 0; s < SS; ++s) xs += xp[(size_t)s * DD];
#pragma unroll
        for (int e = 0; e < EE; ++e) acc[e] += xs * Wg[d * EE + e];
    }

    __shared__ float red[EE][256];
#pragma unroll
    for (int e = 0; e < EE; ++e) red[e][tid] = acc[e];
    __syncthreads();
    for (int off = 128; off > 0; off >>= 1) {
        if (tid < off) {
#pragma unroll
            for (int e = 0; e < EE; ++e) red[e][tid] += red[e][tid + off];
        }
        __syncthreads();
    }

    if (tid == 0) {
        float lg[EE], p[EE];
        float m = -1e30f;
#pragma unroll
        for (int e = 0; e < EE; ++e) {
            lg[e] = red[e][0] / (float)SS + bg[e];
            m = fmaxf(m, lg[e]);
        }
        float sum = 0.f;
#pragma unroll
        for (int e = 0; e < EE; ++e) { p[e] = expf(lg[e] - m); sum += p[e]; }
        float inv = 1.f / sum;
#pragma unroll
        for (int e = 0; e < EE; ++e) p[e] *= inv;

        int i1 = 0;
        for (int e = 1; e < EE; ++e) if (p[e] > p[i1]) i1 = e;
        int i2 = (i1 == 0) ? 1 : 0;
        for (int e = 0; e < EE; ++e) if (e != i1 && p[e] > p[i2]) i2 = e;

        float* prob_out = out + (size_t)BB * SS * DD;
        float* gate_out = prob_out + BB * KK;
        prob_out[b * KK + 0] = p[i1];
        prob_out[b * KK + 1] = p[i2];
        gate_out[b * KK + 0] = (float)i1;
        gate_out[b * KK + 1] = (float)i2;
        gates[b * KK + 0] = i1;
        gates[b * KK + 1] = i2;
    }
}

// ---------------------------------------------------------------------------
__global__ void sched_kernel(int* __restrict__ wsi)
{
    if (threadIdx.x != 0 || blockIdx.x != 0) return;
    const int* gates = wsi;
    int* spair = wsi + 64;
    int* te_e = wsi + 128;
    int* te_s = wsi + 152;
    int* te_n = wsi + 176;
    int* slotof = wsi + 200;

    int cnt[EE];
    for (int e = 0; e < EE; ++e) cnt[e] = 0;
    for (int p = 0; p < NPAIR; ++p) cnt[gates[p]]++;
    int start[EE + 1];
    start[0] = 0;
    for (int e = 0; e < EE; ++e) start[e + 1] = start[e] + cnt[e];
    int fill[EE];
    for (int e = 0; e < EE; ++e) fill[e] = start[e];
    for (int p = 0; p < NPAIR; ++p) {
        int s = fill[gates[p]]++;
        spair[s] = p;
        slotof[p] = s;
    }

    int t = 0;
    for (int e = 0; e < EE; ++e) {
        for (int o = 0; o < cnt[e]; o += 4) {
            te_e[t] = e;
            te_s[t] = start[e] + o;
            te_n[t] = (cnt[e] - o) < 4 ? (cnt[e] - o) : 4;
            ++t;
        }
    }
    for (; t < MAXT; ++t) te_n[t] = 0;
}

// ---------------------------------------------------------------------------
// x -> bf16 pack (once): 786432 elems, 8/thread
__global__ __launch_bounds__(256) void pack_x(
    const float* __restrict__ x, unsigned short* __restrict__ xbf)
{
    int i = blockIdx.x * 256 + threadIdx.x;   // 384 blocks
    const float4* src = (const float4*)(x + (size_t)i * 8);
    float4 v0 = src[0], v1 = src[1];
    us8 u;
    u[0] = f2bf(v0.x); u[1] = f2bf(v0.y); u[2] = f2bf(v0.z); u[3] = f2bf(v0.w);
    u[4] = f2bf(v1.x); u[5] = f2bf(v1.y); u[6] = f2bf(v1.z); u[7] = f2bf(v1.w);
    *(us8*)(xbf + (size_t)i * 8) = u;
}

// ---------------------------------------------------------------------------
// Fallback init: out = bias sums (down<1> atomics add on top)
__global__ __launch_bounds__(256) void init_kernel(
    const int* __restrict__ gates, const float* __restrict__ b2,
    float* __restrict__ out)
{
    int idx = blockIdx.x * 256 + threadIdx.x;
    if (idx >= BB * SS * DD) return;
    int b = idx / (SS * DD);
    int d = idx % DD;
    int e0 = gates[b * KK + 0];
    int e1 = gates[b * KK + 1];
    out[idx] = b2[e0 * DD + d] + b2[e1 * DD + d];
}

// ---------------------------------------------------------------------------
// Up GEMM: H = gelu(xbf @ W1[e] + b1); BM=128 BN=128 BK=64, 4 waves 2x2
// (wave-tile 64x64), dual reg sets, issue-before-store, NO-DRAIN barriers.
// 1D grid XCD decode: all tiles of one nt share an XCD -> W1 panel L2 reuse.
// gridDim = 8 * MAXT * 3 = 528; nt = grp*8 + xcd (24 nts).
__global__ __launch_bounds__(256, 2) void up_gemm(
    const unsigned short* __restrict__ xbf, const float* __restrict__ W1,
    const float* __restrict__ b1, const int* __restrict__ wsi,
    unsigned short* __restrict__ H)
{
    int bid = blockIdx.x;
    int xcd = bid & 7;
    int r = bid >> 3;
    int tile = r % MAXT;
    int grp = r / MAXT;          // 0..2
    int nt = grp * 8 + xcd;      // 0..23
    int np = wsi[176 + tile];
    if (np == 0) return;
    int e = wsi[128 + tile];
    int slot0 = wsi[152 + tile];
    int tid = threadIdx.x;
    int wid = tid >> 6, lane = tid & 63;
    int wm = wid >> 1, wn = wid & 1;

    __shared__ char lds[65536];

    // A staging (bf16): 128 rows x 8 chunks(8 bf16); 4 chunks/thread
    const unsigned short* asrc[4];
    int aoff[4];
#pragma unroll
    for (int i = 0; i < 4; ++i) {
        int c = tid + i * 256;
        int row = c >> 3, ch = c & 7;
        int lp = row >> 5;
        int lpc = lp < np ? lp : np - 1;
        int pair = wsi[64 + slot0 + lpc];
        int b = pair >> 1;
        asrc[i] = xbf + ((size_t)(b * SS + (row & 31))) * DD + ch * 8;
        aoff[i] = lds_off(row, ch * 16);
    }
    // B staging: [n][k] LDS; 128 n-cols coalesced, k strided; 32 loads/thread
    int n = tid & 127, kq = tid >> 7;   // kq in {0,1}: k-rows kq*32 + j
    const float* bsrc = W1 + ((size_t)e * DD + kq * 32) * FFD + nt * 128 + n;
    int boff[4];
#pragma unroll
    for (int m4 = 0; m4 < 4; ++m4) boff[m4] = lds_off(n, kq * 64 + m4 * 16);

    f32x4 acc[4][4];
#pragma unroll
    for (int i = 0; i < 4; ++i)
#pragma unroll
        for (int j = 0; j < 4; ++j) acc[i][j] = (f32x4)0.f;

    float bB0[32], bB1[32];
    us8 bA0[4], bA1[4];

    auto issue = [&](int k0, float (&bB)[32], us8 (&bA)[4]) {
        const float* wp = bsrc + (size_t)k0 * FFD;   // cold HBM stream first
#pragma unroll
        for (int j = 0; j < 32; ++j) bB[j] = wp[(size_t)j * FFD];
#pragma unroll
        for (int i = 0; i < 4; ++i) bA[i] = *(const us8*)(asrc[i] + k0);
    };
    auto store = [&](int p, const float (&bB)[32], const us8 (&bA)[4]) {
        char* Al = lds + p * 32768;
        char* Bl = Al + 16384;
#pragma unroll
        for (int i = 0; i < 4; ++i) *(us8*)(Al + aoff[i]) = bA[i];
#pragma unroll
        for (int m4 = 0; m4 < 4; ++m4) {
            us8 u;
#pragma unroll
            for (int m = 0; m < 8; ++m) u[m] = f2bf(bB[m4 * 8 + m]);
            *(us8*)(Bl + boff[m4]) = u;
        }
    };
    auto compute = [&](int p) {
        char* Al = lds + p * 32768;
        char* Bl = Al + 16384;
#pragma unroll
        for (int kk = 0; kk < 2; ++kk) {
            int kb = kk * 64 + (lane >> 4) * 16;
            short8 af[4], bf[4];
#pragma unroll
            for (int mf = 0; mf < 4; ++mf)
                af[mf] = *(short8*)(Al + lds_off(wm * 64 + mf * 16 + (lane & 15), kb));
#pragma unroll
            for (int nf = 0; nf < 4; ++nf)
                bf[nf] = *(short8*)(Bl + lds_off(wn * 64 + nf * 16 + (lane & 15), kb));
#pragma unroll
            for (int mf = 0; mf < 4; ++mf)
#pragma unroll
                for (int nf = 0; nf < 4; ++nf)
                    acc[mf][nf] = __builtin_amdgcn_mfma_f32_16x16x32_bf16(
                        af[mf], bf[nf], acc[mf][nf], 0, 0, 0);
        }
    };

    const int steps = 12;   // DD/64
    issue(0, bB0, bA0);
    issue(64, bB1, bA1);
    store(0, bB0, bA0);
    phase_barrier();
    for (int s = 0; s < steps; s += 2) {
        compute(0);
        if (s + 2 < steps) issue((s + 2) * 64, bB0, bA0);
        store(1, bB1, bA1);
        phase_barrier();
        compute(1);
        if (s + 2 < steps) {
            if (s + 3 < steps) issue((s + 3) * 64, bB1, bA1);
            store(0, bB0, bA0);
        }
        phase_barrier();
    }

    // epilogue: bias + exact gelu -> bf16 H (grouped slot rows)
    float bias[4];
#pragma unroll
    for (int nf = 0; nf < 4; ++nf)
        bias[nf] = b1[e * FFD + nt * 128 + wn * 64 + nf * 16 + (lane & 15)];
#pragma unroll
    for (int mf = 0; mf < 4; ++mf) {
#pragma unroll
        for (int i = 0; i < 4; ++i) {
            int row = wm * 64 + mf * 16 + (lane >> 4) * 4 + i;
            if ((row >> 5) >= np) continue;
            size_t srow = (size_t)(slot0 * 32 + row);
#pragma unroll
            for (int nf = 0; nf < 4; ++nf) {
                int f = nt * 128 + wn * 64 + nf * 16 + (lane & 15);
                float h = acc[mf][nf][i] + bias[nf];
                float g = 0.5f * h * (1.0f + erff(h * 0.70710678118654752f));
                H[srow * FFD + f] = f2bf(g);
            }
        }
    }
}

// ---------------------------------------------------------------------------
// Down GEMM: BM=128 BN=128 BK=64, z=2 K-split (steps=24), dual reg sets,
// NO-DRAIN barriers. 1D grid XCD decode: all tiles of one (nt,z) share an
// XCD -> W2 panel (786KB) stays in that XCD's 4MB L2 across same-expert
// tiles. gridDim = 8 * MAXT * 2 = 352; pairidx = grp*8+xcd; 12 real.
template<int MODE>
__global__ __launch_bounds__(256, 2) void down_gemm(
    const unsigned short* __restrict__ H, const float* __restrict__ W2,
    const int* __restrict__ wsi, unsigned short* __restrict__ part,
    float* __restrict__ out)
{
    int bid = blockIdx.x;
    int xcd = bid & 7;
    int r = bid >> 3;
    int tile = r % MAXT;
    int grp = r / MAXT;              // 0..1
    int pairidx = grp * 8 + xcd;     // 0..15
    if (pairidx >= 12) return;
    int nt = pairidx % 6;
    int z = pairidx / 6;             // 0..1
    int np = wsi[176 + tile];
    if (np == 0) return;
    int e = wsi[128 + tile];
    int slot0 = wsi[152 + tile];
    int zb = z * (FFD / 2);
    int tid = threadIdx.x;
    int wid = tid >> 6, lane = tid & 63;
    int wm = wid >> 1, wn = wid & 1;

    __shared__ char lds[65536];

    // A staging (H bf16, grouped rows; clamp tail)
    const unsigned short* asrc[4];
    int aoff[4];
#pragma unroll
    for (int i = 0; i < 4; ++i) {
        int c = tid + i * 256;
        int row = c >> 3, ch = c & 7;
        int rc = row < np * 32 ? row : np * 32 - 1;
        asrc[i] = H + (size_t)(slot0 * 32 + rc) * FFD + zb + ch * 8;
        aoff[i] = lds_off(row, ch * 16);
    }
    int n = tid & 127, kq = tid >> 7;
    const float* bsrc = W2 + ((size_t)e * FFD + zb + kq * 32) * DD + nt * 128 + n;
    int boff[4];
#pragma unroll
    for (int m4 = 0; m4 < 4; ++m4) boff[m4] = lds_off(n, kq * 64 + m4 * 16);

    f32x4 acc[4][4];
#pragma unroll
    for (int i = 0; i < 4; ++i)
#pragma unroll
        for (int j = 0; j < 4; ++j) acc[i][j] = (f32x4)0.f;

    float bB0[32], bB1[32];
    us8 bA0[4], bA1[4];

    auto issue = [&](int k0, float (&bB)[32], us8 (&bA)[4]) {
        const float* wp = bsrc + (size_t)k0 * DD;
#pragma unroll
        for (int j = 0; j < 32; ++j) bB[j] = wp[(size_t)j * DD];
#pragma unroll
        for (int i = 0; i < 4; ++i) bA[i] = *(const us8*)(asrc[i] + k0);
    };
    auto store = [&](int p, const float (&bB)[32], const us8 (&bA)[4]) {
        char* Al = lds + p * 32768;
        char* Bl = Al + 16384;
#pragma unroll
        for (int i = 0; i < 4; ++i) *(us8*)(Al + aoff[i]) = bA[i];
#pragma unroll
        for (int m4 = 0; m4 < 4; ++m4) {
            us8 u;
#pragma unroll
            for (int m = 0; m < 8; ++m) u[m] = f2bf(bB[m4 * 8 + m]);
            *(us8*)(Bl + boff[m4]) = u;
        }
    };
    auto compute = [&](int p) {
        char* Al = lds + p * 32768;
        char* Bl = Al + 16384;
#pragma unroll
        for (int kk = 0; kk < 2; ++kk) {
            int kb = kk * 64 + (lane >> 4) * 16;
            short8 af[4], bf[4];
#pragma unroll
            for (int mf = 0; mf < 4; ++mf)
                af[mf] = *(short8*)(Al + lds_off(wm * 64 + mf * 16 + (lane & 15), kb));
#pragma unroll
            for (int nf = 0; nf < 4; ++nf)
                bf[nf] = *(short8*)(Bl + lds_off(wn * 64 + nf * 16 + (lane & 15), kb));
#pragma unroll
            for (int mf = 0; mf < 4; ++mf)
#pragma unroll
                for (int nf = 0; nf < 4; ++nf)
                    acc[mf][nf] = __builtin_amdgcn_mfma_f32_16x16x32_bf16(
                        af[mf], bf[nf], acc[mf][nf], 0, 0, 0);
        }
    };

    const int steps = 24;   // (FFD/2)/64
    issue(0, bB0, bA0);
    issue(64, bB1, bA1);
    store(0, bB0, bA0);
    phase_barrier();
    for (int s = 0; s < steps; s += 2) {
        compute(0);
        if (s + 2 < steps) issue((s + 2) * 64, bB0, bA0);
        store(1, bB1, bA1);
        phase_barrier();
        compute(1);
        if (s + 2 < steps) {
            if (s + 3 < steps) issue((s + 3) * 64, bB1, bA1);
            store(0, bB0, bA0);
        }
        phase_barrier();
    }

    // epilogue
#pragma unroll
    for (int mf = 0; mf < 4; ++mf) {
#pragma unroll
        for (int i = 0; i < 4; ++i) {
            int row = wm * 64 + mf * 16 + (lane >> 4) * 4 + i;
            int lp = row >> 5;
            if (lp >= np) continue;
            int col = nt * 128 + wn * 64 + (lane & 15);
            if (MODE == 0) {
                size_t srow = (size_t)(slot0 * 32 + row);
                unsigned short* pp = part + (size_t)z * PZ + srow * DD + col;
#pragma unroll
                for (int nf = 0; nf < 4; ++nf) pp[nf * 16] = f2bf(acc[mf][nf][i]);
            } else {
                int pair = wsi[64 + slot0 + lp];
                int b = pair >> 1;
                int sI = row & 31;
                float* op = out + ((size_t)(b * SS + sI)) * DD + col;
#pragma unroll
                for (int nf = 0; nf < 4; ++nf)
                    atomicAdd(op + nf * 16, acc[mf][nf][i]);
            }
        }
    }
}

// ---------------------------------------------------------------------------
// Reduce: out[b,s,d0..d0+7] = sum_{k,z} part[z][slot(b,k)*32+s][d] + biases
__global__ __launch_bounds__(512) void reduce_kernel(
    const unsigned short* __restrict__ part, const int* __restrict__ wsi,
    const float* __restrict__ b2, float* __restrict__ out)
{
    int i8 = blockIdx.x * 512 + threadIdx.x;    // 98304 threads, 8 elems each
    int flat = i8 * 8;
    int b = flat / (SS * DD);
    int r = flat - b * (SS * DD);
    int s = r / DD;
    int d = r - s * DD;

    int e0 = wsi[b * KK + 0];
    int e1 = wsi[b * KK + 1];
    int sl0 = wsi[200 + b * KK + 0];
    int sl1 = wsi[200 + b * KK + 1];
    size_t r0 = (size_t)(sl0 * 32 + s) * DD + d;
    size_t r1 = (size_t)(sl1 * 32 + s) * DD + d;

    const float* bb0 = b2 + e0 * DD + d;
    const float* bb1 = b2 + e1 * DD + d;

    float v[8];
#pragma unroll
    for (int j = 0; j < 8; ++j) v[j] = bb0[j] + bb1[j];
#pragma unroll
    for (int z = 0; z < 2; ++z) {
        us8 p0 = *(const us8*)(part + (size_t)z * PZ + r0);
        us8 p1 = *(const us8*)(part + (size_t)z * PZ + r1);
#pragma unroll
        for (int j = 0; j < 8; ++j) v[j] += bf2f(p0[j]) + bf2f(p1[j]);
    }
    float4* op = (float4*)(out + flat);
    op[0] = make_float4(v[0], v[1], v[2], v[3]);
    op[1] = make_float4(v[4], v[5], v[6], v[7]);
}

// ---------------------------------------------------------------------------
extern "C" void kernel_launch(void* const* d_in, const int* in_sizes, int n_in,
                              void* d_out, int out_size, void* d_ws, size_t ws_size,
                              hipStream_t stream) {
    const float* x  = (const float*)d_in[0];
    const float* Wg = (const float*)d_in[2];
    const float* bg = (const float*)d_in[3];
    const float* W1 = (const float*)d_in[4];
    const float* b1 = (const float*)d_in[5];
    const float* W2 = (const float*)d_in[6];
    const float* b2 = (const float*)d_in[7];
    float* out = (float*)d_out;

    int* wsi = (int*)d_ws;
    unsigned short* H    = (unsigned short*)((char*)d_ws + H_OFF);
    unsigned short* xbf  = (unsigned short*)((char*)d_ws + XBF_OFF);
    unsigned short* part = (unsigned short*)((char*)d_ws + PART_OFF);
    // xbf/part overlay safe: pack_x -> up_gemm (reads xbf) -> down_gemm
    // (writes part) are stream-ordered.

    gate_kernel<<<BB, 256, 0, stream>>>(x, Wg, bg, out, wsi);
    sched_kernel<<<1, 64, 0, stream>>>(wsi);
    pack_x<<<(BB * SS * DD) / (256 * 8), 256, 0, stream>>>(x, xbf);
    up_gemm<<<8 * MAXT * 3, 256, 0, stream>>>(xbf, W1, b1, wsi, H);

    if (ws_size >= WS_MAIN) {
        down_gemm<0><<<8 * MAXT * 2, 256, 0, stream>>>(H, W2, wsi, part, out);
        reduce_kernel<<<(BB * SS * DD) / (512 * 8), 512, 0, stream>>>(
            part, wsi, b2, out);
    } else {
        init_kernel<<<(BB * SS * DD + 255) / 256, 256, 0, stream>>>(wsi, b2, out);
        down_gemm<1><<<8 * MAXT * 2, 256, 0, stream>>>(H, W2, wsi, part, out);
    }
}

// Round 15
// 109.657 us; speedup vs baseline: 1.0742x; 1.0174x over previous
//
#include <hip/hip_runtime.h>
#include <hip/hip_bf16.h>
#include <math.h>

#define BB 32
#define SS 32
#define DD 768
#define FFD 3072
#define EE 8
#define KK 2
#define NPAIR 64
#define MAXT 22   // tiles of 4 pairs (BM=128)

typedef __attribute__((ext_vector_type(8))) short short8;
typedef __attribute__((ext_vector_type(4))) float f32x4;
typedef __attribute__((ext_vector_type(8))) unsigned short us8;

// ws layout:
//   ints [0..63] gates, [64..127] spair, [128..149] te_e, [152..173] te_s,
//        [176..197] te_np, [200..263] slot_of_pair   (ends @ byte 1056)
//   H    bf16 [2048][3072]    @ 4096        (12.58 MB)
//   xbf  bf16 [1024][768]     @ XBF_OFF     (1.57 MB)  -- dead after up_gemm
//   part bf16 [2][2048][768]  @ PART_OFF = XBF_OFF (overlay)   (6.29 MB)
//   end ~18.9 MB  (< R7-proven 25.2 MB resident bound)

#define H_OFF    4096
#define XBF_OFF  (H_OFF + 12582912)
#define PART_OFF XBF_OFF
#define PZ       (2048 * 768)
#define WS_MAIN  ((size_t)PART_OFF + 2ull * PZ * 2ull)

__device__ __forceinline__ unsigned short f2bf(float f) {
    __hip_bfloat16 h = __float2bfloat16(f);
    return __builtin_bit_cast(unsigned short, h);
}
__device__ __forceinline__ float bf2f(unsigned short u) {
    __hip_bfloat16 h = __builtin_bit_cast(__hip_bfloat16, u);
    return __bfloat162float(h);
}

// proven swizzle: 128B rows, XOR bits 4-6 with row&7
__device__ __forceinline__ int lds_off(int row, int byte_in_row) {
    return row * 128 + (byte_in_row ^ ((row & 7) << 4));
}

// lgkm-only barrier (R8/R9/R14-proven correct): orders LDS write->read
// across waves WITHOUT draining vmcnt, so global-load prefetch issued this
// phase stays in flight; compiler adds per-register vmcnt waits at uses.
__device__ __forceinline__ void phase_barrier() {
    __builtin_amdgcn_sched_barrier(0);
    asm volatile("s_waitcnt lgkmcnt(0)" ::: "memory");
    __builtin_amdgcn_s_barrier();
    __builtin_amdgcn_sched_barrier(0);
}

// ---------------------------------------------------------------------------
__global__ __launch_bounds__(256) void gate_kernel(
    const float* __restrict__ x, const float* __restrict__ Wg,
    const float* __restrict__ bg, float* __restrict__ out,
    int* __restrict__ gates)
{
    int b = blockIdx.x;
    int tid = threadIdx.x;

    float acc[EE];
#pragma unroll
    for (int e = 0; e < EE; ++e) acc[e] = 0.f;

    for (int d = tid; d < DD; d += 256) {
        float xs = 0.f;
        const float* xp = x + (size_t)b * SS * DD + d;
#pragma unroll
        for (int s = 0; s < SS; ++s) xs += xp[(size_t)s * DD];
#pragma unroll
        for (int e = 0; e < EE; ++e) acc[e] += xs * Wg[d * EE + e];
    }

    __shared__ float red[EE][256];
#pragma unroll
    for (int e = 0; e < EE; ++e) red[e][tid] = acc[e];
    __syncthreads();
    for (int off = 128; off > 0; off >>= 1) {
        if (tid < off) {
#pragma unroll
            for (int e = 0; e < EE; ++e) red[e][tid] += red[e][tid + off];
        }
        __syncthreads();
    }

    if (tid == 0) {
        float lg[EE], p[EE];
        float m = -1e30f;
#pragma unroll
        for (int e = 0; e < EE; ++e) {
            lg[e] = red[e][0] / (float)SS + bg[e];
            m = fmaxf(m, lg[e]);
        }
        float sum = 0.f;
#pragma unroll
        for (int e = 0; e < EE; ++e) { p[e] = expf(lg[e] - m); sum += p[e]; }
        float inv = 1.f / sum;
#pragma unroll
        for (int e = 0; e < EE; ++e) p[e] *= inv;

        int i1 = 0;
        for (int e = 1; e < EE; ++e) if (p[e] > p[i1]) i1 = e;
        int i2 = (i1 == 0) ? 1 : 0;
        for (int e = 0; e < EE; ++e) if (e != i1 && p[e] > p[i2]) i2 = e;

        float* prob_out = out + (size_t)BB * SS * DD;
        float* gate_out = prob_out + BB * KK;
        prob_out[b * KK + 0] = p[i1];
        prob_out[b * KK + 1] = p[i2];
        gate_out[b * KK + 0] = (float)i1;
        gate_out[b * KK + 1] = (float)i2;
        gates[b * KK + 0] = i1;
        gates[b * KK + 1] = i2;
    }
}

// ---------------------------------------------------------------------------
__global__ void sched_kernel(int* __restrict__ wsi)
{
    if (threadIdx.x != 0 || blockIdx.x != 0) return;
    const int* gates = wsi;
    int* spair = wsi + 64;
    int* te_e = wsi + 128;
    int* te_s = wsi + 152;
    int* te_n = wsi + 176;
    int* slotof = wsi + 200;

    int cnt[EE];
    for (int e = 0; e < EE; ++e) cnt[e] = 0;
    for (int p = 0; p < NPAIR; ++p) cnt[gates[p]]++;
    int start[EE + 1];
    start[0] = 0;
    for (int e = 0; e < EE; ++e) start[e + 1] = start[e] + cnt[e];
    int fill[EE];
    for (int e = 0; e < EE; ++e) fill[e] = start[e];
    for (int p = 0; p < NPAIR; ++p) {
        int s = fill[gates[p]]++;
        spair[s] = p;
        slotof[p] = s;
    }

    int t = 0;
    for (int e = 0; e < EE; ++e) {
        for (int o = 0; o < cnt[e]; o += 4) {
            te_e[t] = e;
            te_s[t] = start[e] + o;
            te_n[t] = (cnt[e] - o) < 4 ? (cnt[e] - o) : 4;
            ++t;
        }
    }
    for (; t < MAXT; ++t) te_n[t] = 0;
}

// ---------------------------------------------------------------------------
// x -> bf16 pack (once): 786432 elems, 8/thread
__global__ __launch_bounds__(256) void pack_x(
    const float* __restrict__ x, unsigned short* __restrict__ xbf)
{
    int i = blockIdx.x * 256 + threadIdx.x;   // 384 blocks
    const float4* src = (const float4*)(x + (size_t)i * 8);
    float4 v0 = src[0], v1 = src[1];
    us8 u;
    u[0] = f2bf(v0.x); u[1] = f2bf(v0.y); u[2] = f2bf(v0.z); u[3] = f2bf(v0.w);
    u[4] = f2bf(v1.x); u[5] = f2bf(v1.y); u[6] = f2bf(v1.z); u[7] = f2bf(v1.w);
    *(us8*)(xbf + (size_t)i * 8) = u;
}

// ---------------------------------------------------------------------------
// Fallback init: out = bias sums (down<1> atomics add on top)
__global__ __launch_bounds__(256) void init_kernel(
    const int* __restrict__ gates, const float* __restrict__ b2,
    float* __restrict__ out)
{
    int idx = blockIdx.x * 256 + threadIdx.x;
    if (idx >= BB * SS * DD) return;
    int b = idx / (SS * DD);
    int d = idx % DD;
    int e0 = gates[b * KK + 0];
    int e1 = gates[b * KK + 1];
    out[idx] = b2[e0 * DD + d] + b2[e1 * DD + d];
}

// ---------------------------------------------------------------------------
// Up GEMM (R14 version — measured ~30us): BM=128 BN=128 BK=64, 4 waves 2x2
// (wave-tile 64x64), dual reg sets, issue-before-store, NO-DRAIN barriers.
// 1D grid XCD decode (24 nt-groups = 3 balanced XCD rounds -> W1 panel L2
// reuse pays here). gridDim = 8 * MAXT * 3 = 528; nt = grp*8 + xcd.
__global__ __launch_bounds__(256, 2) void up_gemm(
    const unsigned short* __restrict__ xbf, const float* __restrict__ W1,
    const float* __restrict__ b1, const int* __restrict__ wsi,
    unsigned short* __restrict__ H)
{
    int bid = blockIdx.x;
    int xcd = bid & 7;
    int r = bid >> 3;
    int tile = r % MAXT;
    int grp = r / MAXT;          // 0..2
    int nt = grp * 8 + xcd;      // 0..23
    int np = wsi[176 + tile];
    if (np == 0) return;
    int e = wsi[128 + tile];
    int slot0 = wsi[152 + tile];
    int tid = threadIdx.x;
    int wid = tid >> 6, lane = tid & 63;
    int wm = wid >> 1, wn = wid & 1;

    __shared__ char lds[65536];

    // A staging (bf16): 128 rows x 8 chunks(8 bf16); 4 chunks/thread
    const unsigned short* asrc[4];
    int aoff[4];
#pragma unroll
    for (int i = 0; i < 4; ++i) {
        int c = tid + i * 256;
        int row = c >> 3, ch = c & 7;
        int lp = row >> 5;
        int lpc = lp < np ? lp : np - 1;
        int pair = wsi[64 + slot0 + lpc];
        int b = pair >> 1;
        asrc[i] = xbf + ((size_t)(b * SS + (row & 31))) * DD + ch * 8;
        aoff[i] = lds_off(row, ch * 16);
    }
    // B staging: [n][k] LDS; 128 n-cols coalesced, k strided; 32 loads/thread
    int n = tid & 127, kq = tid >> 7;   // kq in {0,1}: k-rows kq*32 + j
    const float* bsrc = W1 + ((size_t)e * DD + kq * 32) * FFD + nt * 128 + n;
    int boff[4];
#pragma unroll
    for (int m4 = 0; m4 < 4; ++m4) boff[m4] = lds_off(n, kq * 64 + m4 * 16);

    f32x4 acc[4][4];
#pragma unroll
    for (int i = 0; i < 4; ++i)
#pragma unroll
        for (int j = 0; j < 4; ++j) acc[i][j] = (f32x4)0.f;

    float bB0[32], bB1[32];
    us8 bA0[4], bA1[4];

    auto issue = [&](int k0, float (&bB)[32], us8 (&bA)[4]) {
        const float* wp = bsrc + (size_t)k0 * FFD;   // cold HBM stream first
#pragma unroll
        for (int j = 0; j < 32; ++j) bB[j] = wp[(size_t)j * FFD];
#pragma unroll
        for (int i = 0; i < 4; ++i) bA[i] = *(const us8*)(asrc[i] + k0);
    };
    auto store = [&](int p, const float (&bB)[32], const us8 (&bA)[4]) {
        char* Al = lds + p * 32768;
        char* Bl = Al + 16384;
#pragma unroll
        for (int i = 0; i < 4; ++i) *(us8*)(Al + aoff[i]) = bA[i];
#pragma unroll
        for (int m4 = 0; m4 < 4; ++m4) {
            us8 u;
#pragma unroll
            for (int m = 0; m < 8; ++m) u[m] = f2bf(bB[m4 * 8 + m]);
            *(us8*)(Bl + boff[m4]) = u;
        }
    };
    auto compute = [&](int p) {
        char* Al = lds + p * 32768;
        char* Bl = Al + 16384;
#pragma unroll
        for (int kk = 0; kk < 2; ++kk) {
            int kb = kk * 64 + (lane >> 4) * 16;
            short8 af[4], bf[4];
#pragma unroll
            for (int mf = 0; mf < 4; ++mf)
                af[mf] = *(short8*)(Al + lds_off(wm * 64 + mf * 16 + (lane & 15), kb));
#pragma unroll
            for (int nf = 0; nf < 4; ++nf)
                bf[nf] = *(short8*)(Bl + lds_off(wn * 64 + nf * 16 + (lane & 15), kb));
#pragma unroll
            for (int mf = 0; mf < 4; ++mf)
#pragma unroll
                for (int nf = 0; nf < 4; ++nf)
                    acc[mf][nf] = __builtin_amdgcn_mfma_f32_16x16x32_bf16(
                        af[mf], bf[nf], acc[mf][nf], 0, 0, 0);
        }
    };

    const int steps = 12;   // DD/64
    issue(0, bB0, bA0);
    issue(64, bB1, bA1);
    store(0, bB0, bA0);
    phase_barrier();
    for (int s = 0; s < steps; s += 2) {
        compute(0);
        if (s + 2 < steps) issue((s + 2) * 64, bB0, bA0);
        store(1, bB1, bA1);
        phase_barrier();
        compute(1);
        if (s + 2 < steps) {
            if (s + 3 < steps) issue((s + 3) * 64, bB1, bA1);
            store(0, bB0, bA0);
        }
        phase_barrier();
    }

    // epilogue: bias + exact gelu -> bf16 H (grouped slot rows)
    float bias[4];
#pragma unroll
    for (int nf = 0; nf < 4; ++nf)
        bias[nf] = b1[e * FFD + nt * 128 + wn * 64 + nf * 16 + (lane & 15)];
#pragma unroll
    for (int mf = 0; mf < 4; ++mf) {
#pragma unroll
        for (int i = 0; i < 4; ++i) {
            int row = wm * 64 + mf * 16 + (lane >> 4) * 4 + i;
            if ((row >> 5) >= np) continue;
            size_t srow = (size_t)(slot0 * 32 + row);
#pragma unroll
            for (int nf = 0; nf < 4; ++nf) {
                int f = nt * 128 + wn * 64 + nf * 16 + (lane & 15);
                float h = acc[mf][nf][i] + bias[nf];
                float g = 0.5f * h * (1.0f + erff(h * 0.70710678118654752f));
                H[srow * FFD + f] = f2bf(g);
            }
        }
    }
}

// ---------------------------------------------------------------------------
// Down GEMM (R11 grid — measured 46us — + no-drain barriers as the single
// delta): BM=128 BN=128 BK=64, z=2 K-split (steps=24), dual reg sets,
// issue-before-store. Default round-robin XCD mapping (only 12 panel-groups:
// XCD pinning proved harmful in R14 — starved XCDs + per-XCD BW cap).
// grid dim3(6 nt, MAXT, 2 z). MODE 0: bf16 partials; MODE 1: atomic.
template<int MODE>
__global__ __launch_bounds__(256, 2) void down_gemm(
    const unsigned short* __restrict__ H, const float* __restrict__ W2,
    const int* __restrict__ wsi, unsigned short* __restrict__ part,
    float* __restrict__ out)
{
    int nt = blockIdx.x;             // 0..5
    int tile = blockIdx.y;           // 0..MAXT-1
    int z = blockIdx.z;              // 0..1
    int np = wsi[176 + tile];
    if (np == 0) return;
    int e = wsi[128 + tile];
    int slot0 = wsi[152 + tile];
    int zb = z * (FFD / 2);
    int tid = threadIdx.x;
    int wid = tid >> 6, lane = tid & 63;
    int wm = wid >> 1, wn = wid & 1;

    __shared__ char lds[65536];

    // A staging (H bf16, grouped rows; clamp tail)
    const unsigned short* asrc[4];
    int aoff[4];
#pragma unroll
    for (int i = 0; i < 4; ++i) {
        int c = tid + i * 256;
        int row = c >> 3, ch = c & 7;
        int rc = row < np * 32 ? row : np * 32 - 1;
        asrc[i] = H + (size_t)(slot0 * 32 + rc) * FFD + zb + ch * 8;
        aoff[i] = lds_off(row, ch * 16);
    }
    int n = tid & 127, kq = tid >> 7;
    const float* bsrc = W2 + ((size_t)e * FFD + zb + kq * 32) * DD + nt * 128 + n;
    int boff[4];
#pragma unroll
    for (int m4 = 0; m4 < 4; ++m4) boff[m4] = lds_off(n, kq * 64 + m4 * 16);

    f32x4 acc[4][4];
#pragma unroll
    for (int i = 0; i < 4; ++i)
#pragma unroll
        for (int j = 0; j < 4; ++j) acc[i][j] = (f32x4)0.f;

    float bB0[32], bB1[32];
    us8 bA0[4], bA1[4];

    auto issue = [&](int k0, float (&bB)[32], us8 (&bA)[4]) {
        const float* wp = bsrc + (size_t)k0 * DD;
#pragma unroll
        for (int j = 0; j < 32; ++j) bB[j] = wp[(size_t)j * DD];
#pragma unroll
        for (int i = 0; i < 4; ++i) bA[i] = *(const us8*)(asrc[i] + k0);
    };
    auto store = [&](int p, const float (&bB)[32], const us8 (&bA)[4]) {
        char* Al = lds + p * 32768;
        char* Bl = Al + 16384;
#pragma unroll
        for (int i = 0; i < 4; ++i) *(us8*)(Al + aoff[i]) = bA[i];
#pragma unroll
        for (int m4 = 0; m4 < 4; ++m4) {
            us8 u;
#pragma unroll
            for (int m = 0; m < 8; ++m) u[m] = f2bf(bB[m4 * 8 + m]);
            *(us8*)(Bl + boff[m4]) = u;
        }
    };
    auto compute = [&](int p) {
        char* Al = lds + p * 32768;
        char* Bl = Al + 16384;
#pragma unroll
        for (int kk = 0; kk < 2; ++kk) {
            int kb = kk * 64 + (lane >> 4) * 16;
            short8 af[4], bf[4];
#pragma unroll
            for (int mf = 0; mf < 4; ++mf)
                af[mf] = *(short8*)(Al + lds_off(wm * 64 + mf * 16 + (lane & 15), kb));
#pragma unroll
            for (int nf = 0; nf < 4; ++nf)
                bf[nf] = *(short8*)(Bl + lds_off(wn * 64 + nf * 16 + (lane & 15), kb));
#pragma unroll
            for (int mf = 0; mf < 4; ++mf)
#pragma unroll
                for (int nf = 0; nf < 4; ++nf)
                    acc[mf][nf] = __builtin_amdgcn_mfma_f32_16x16x32_bf16(
                        af[mf], bf[nf], acc[mf][nf], 0, 0, 0);
        }
    };

    const int steps = 24;   // (FFD/2)/64
    issue(0, bB0, bA0);
    issue(64, bB1, bA1);
    store(0, bB0, bA0);
    phase_barrier();
    for (int s = 0; s < steps; s += 2) {
        compute(0);
        if (s + 2 < steps) issue((s + 2) * 64, bB0, bA0);
        store(1, bB1, bA1);
        phase_barrier();
        compute(1);
        if (s + 2 < steps) {
            if (s + 3 < steps) issue((s + 3) * 64, bB1, bA1);
            store(0, bB0, bA0);
        }
        phase_barrier();
    }

    // epilogue
#pragma unroll
    for (int mf = 0; mf < 4; ++mf) {
#pragma unroll
        for (int i = 0; i < 4; ++i) {
            int row = wm * 64 + mf * 16 + (lane >> 4) * 4 + i;
            int lp = row >> 5;
            if (lp >= np) continue;
            int col = nt * 128 + wn * 64 + (lane & 15);
            if (MODE == 0) {
                size_t srow = (size_t)(slot0 * 32 + row);
                unsigned short* pp = part + (size_t)z * PZ + srow * DD + col;
#pragma unroll
                for (int nf = 0; nf < 4; ++nf) pp[nf * 16] = f2bf(acc[mf][nf][i]);
            } else {
                int pair = wsi[64 + slot0 + lp];
                int b = pair >> 1;
                int sI = row & 31;
                float* op = out + ((size_t)(b * SS + sI)) * DD + col;
#pragma unroll
                for (int nf = 0; nf < 4; ++nf)
                    atomicAdd(op + nf * 16, acc[mf][nf][i]);
            }
        }
    }
}

// ---------------------------------------------------------------------------
// Reduce: out[b,s,d0..d0+7] = sum_{k,z} part[z][slot(b,k)*32+s][d] + biases
__global__ __launch_bounds__(512) void reduce_kernel(
    const unsigned short* __restrict__ part, const int* __restrict__ wsi,
    const float* __restrict__ b2, float* __restrict__ out)
{
    int i8 = blockIdx.x * 512 + threadIdx.x;    // 98304 threads, 8 elems each
    int flat = i8 * 8;
    int b = flat / (SS * DD);
    int r = flat - b * (SS * DD);
    int s = r / DD;
    int d = r - s * DD;

    int e0 = wsi[b * KK + 0];
    int e1 = wsi[b * KK + 1];
    int sl0 = wsi[200 + b * KK + 0];
    int sl1 = wsi[200 + b * KK + 1];
    size_t r0 = (size_t)(sl0 * 32 + s) * DD + d;
    size_t r1 = (size_t)(sl1 * 32 + s) * DD + d;

    const float* bb0 = b2 + e0 * DD + d;
    const float* bb1 = b2 + e1 * DD + d;

    float v[8];
#pragma unroll
    for (int j = 0; j < 8; ++j) v[j] = bb0[j] + bb1[j];
#pragma unroll
    for (int z = 0; z < 2; ++z) {
        us8 p0 = *(const us8*)(part + (size_t)z * PZ + r0);
        us8 p1 = *(const us8*)(part + (size_t)z * PZ + r1);
#pragma unroll
        for (int j = 0; j < 8; ++j) v[j] += bf2f(p0[j]) + bf2f(p1[j]);
    }
    float4* op = (float4*)(out + flat);
    op[0] = make_float4(v[0], v[1], v[2], v[3]);
    op[1] = make_float4(v[4], v[5], v[6], v[7]);
}

// ---------------------------------------------------------------------------
extern "C" void kernel_launch(void* const* d_in, const int* in_sizes, int n_in,
                              void* d_out, int out_size, void* d_ws, size_t ws_size,
                              hipStream_t stream) {
    const float* x  = (const float*)d_in[0];
    const float* Wg = (const float*)d_in[2];
    const float* bg = (const float*)d_in[3];
    const float* W1 = (const float*)d_in[4];
    const float* b1 = (const float*)d_in[5];
    const float* W2 = (const float*)d_in[6];
    const float* b2 = (const float*)d_in[7];
    float* out = (float*)d_out;

    int* wsi = (int*)d_ws;
    unsigned short* H    = (unsigned short*)((char*)d_ws + H_OFF);
    unsigned short* xbf  = (unsigned short*)((char*)d_ws + XBF_OFF);
    unsigned short* part = (unsigned short*)((char*)d_ws + PART_OFF);
    // xbf/part overlay safe: pack_x -> up_gemm (reads xbf) -> down_gemm
    // (writes part) are stream-ordered.

    gate_kernel<<<BB, 256, 0, stream>>>(x, Wg, bg, out, wsi);
    sched_kernel<<<1, 64, 0, stream>>>(wsi);
    pack_x<<<(BB * SS * DD) / (256 * 8), 256, 0, stream>>>(x, xbf);
    up_gemm<<<8 * MAXT * 3, 256, 0, stream>>>(xbf, W1, b1, wsi, H);

    if (ws_size >= WS_MAIN) {
        down_gemm<0><<<dim3(6, MAXT, 2), 256, 0, stream>>>(H, W2, wsi, part, out);
        reduce_kernel<<<(BB * SS * DD) / (512 * 8), 512, 0, stream>>>(
            part, wsi, b2, out);
    } else {
        init_kernel<<<(BB * SS * DD + 255) / 256, 256, 0, stream>>>(wsi, b2, out);
        down_gemm<1><<<dim3(6, MAXT, 2), 256, 0, stream>>>(H, W2, wsi, part, out);
    }
}

// Round 16
// 82.145 us; speedup vs baseline: 1.4339x; 1.3349x over previous
//
#include <hip/hip_runtime.h>
#include <hip/hip_bf16.h>
#include <math.h>

#define BB 32
#define SS 32
#define DD 768
#define FFD 3072
#define EE 8
#define KK 2
#define NPAIR 64
#define MAXT 22   // tiles of 4 pairs (BM=128)

typedef __attribute__((ext_vector_type(8))) short short8;
typedef __attribute__((ext_vector_type(4))) float f32x4;
typedef __attribute__((ext_vector_type(8))) unsigned short us8;

// ws layout:
//   ints [0..63] gates, [64..127] spair, [128..149] te_e, [152..173] te_s,
//        [176..197] te_np, [200..263] slot_of_pair   (ends @ byte 1056)
//   H    bf16 [2048][3072]    @ 4096        (12.58 MB)
//   xbf  bf16 [1024][768]     @ XBF_OFF     (1.57 MB)  -- dead after up_gemm
//   part bf16 [4][2048][768]  @ PART_OFF = XBF_OFF (overlay)   (12.58 MB)
//   end = 25,169,920 B (R12-proven resident)

#define H_OFF    4096
#define XBF_OFF  (H_OFF + 12582912)
#define PART_OFF XBF_OFF
#define PZ       (2048 * 768)
#define WS_MAIN  ((size_t)PART_OFF + 4ull * PZ * 2ull)

__device__ __forceinline__ unsigned short f2bf(float f) {
    __hip_bfloat16 h = __float2bfloat16(f);
    return __builtin_bit_cast(unsigned short, h);
}
__device__ __forceinline__ float bf2f(unsigned short u) {
    __hip_bfloat16 h = __builtin_bit_cast(__hip_bfloat16, u);
    return __bfloat162float(h);
}

// proven swizzle: 128B rows, XOR bits 4-6 with row&7
__device__ __forceinline__ int lds_off(int row, int byte_in_row) {
    return row * 128 + (byte_in_row ^ ((row & 7) << 4));
}

// lgkm-only barrier (helps UP only — R15 showed it hurts down):
__device__ __forceinline__ void phase_barrier() {
    __builtin_amdgcn_sched_barrier(0);
    asm volatile("s_waitcnt lgkmcnt(0)" ::: "memory");
    __builtin_amdgcn_s_barrier();
    __builtin_amdgcn_sched_barrier(0);
}

// ---------------------------------------------------------------------------
__global__ __launch_bounds__(256) void gate_kernel(
    const float* __restrict__ x, const float* __restrict__ Wg,
    const float* __restrict__ bg, float* __restrict__ out,
    int* __restrict__ gates)
{
    int b = blockIdx.x;
    int tid = threadIdx.x;

    float acc[EE];
#pragma unroll
    for (int e = 0; e < EE; ++e) acc[e] = 0.f;

    for (int d = tid; d < DD; d += 256) {
        float xs = 0.f;
        const float* xp = x + (size_t)b * SS * DD + d;
#pragma unroll
        for (int s = 0; s < SS; ++s) xs += xp[(size_t)s * DD];
#pragma unroll
        for (int e = 0; e < EE; ++e) acc[e] += xs * Wg[d * EE + e];
    }

    __shared__ float red[EE][256];
#pragma unroll
    for (int e = 0; e < EE; ++e) red[e][tid] = acc[e];
    __syncthreads();
    for (int off = 128; off > 0; off >>= 1) {
        if (tid < off) {
#pragma unroll
            for (int e = 0; e < EE; ++e) red[e][tid] += red[e][tid + off];
        }
        __syncthreads();
    }

    if (tid == 0) {
        float lg[EE], p[EE];
        float m = -1e30f;
#pragma unroll
        for (int e = 0; e < EE; ++e) {
            lg[e] = red[e][0] / (float)SS + bg[e];
            m = fmaxf(m, lg[e]);
        }
        float sum = 0.f;
#pragma unroll
        for (int e = 0; e < EE; ++e) { p[e] = expf(lg[e] - m); sum += p[e]; }
        float inv = 1.f / sum;
#pragma unroll
        for (int e = 0; e < EE; ++e) p[e] *= inv;

        int i1 = 0;
        for (int e = 1; e < EE; ++e) if (p[e] > p[i1]) i1 = e;
        int i2 = (i1 == 0) ? 1 : 0;
        for (int e = 0; e < EE; ++e) if (e != i1 && p[e] > p[i2]) i2 = e;

        float* prob_out = out + (size_t)BB * SS * DD;
        float* gate_out = prob_out + BB * KK;
        prob_out[b * KK + 0] = p[i1];
        prob_out[b * KK + 1] = p[i2];
        gate_out[b * KK + 0] = (float)i1;
        gate_out[b * KK + 1] = (float)i2;
        gates[b * KK + 0] = i1;
        gates[b * KK + 1] = i2;
    }
}

// ---------------------------------------------------------------------------
// Parallel schedule (was 1-thread serial ~200 dependent global ops):
// 64 threads, gates in LDS, rank-by-scan; thread 0 builds the small tile
// table from LDS counts. ~2us instead of O(10-30us).
__global__ __launch_bounds__(64) void sched_kernel(int* __restrict__ wsi)
{
    __shared__ int g[NPAIR];
    __shared__ int cnt[EE];
    __shared__ int start[EE + 1];
    int p = threadIdx.x;            // 0..63

    g[p] = wsi[p];
    __syncthreads();

    if (p < EE) {
        int c = 0;
        for (int q = 0; q < NPAIR; ++q) c += (g[q] == p);
        cnt[p] = c;
    }
    __syncthreads();
    if (p == 0) {
        start[0] = 0;
        for (int e = 0; e < EE; ++e) start[e + 1] = start[e] + cnt[e];
    }
    __syncthreads();

    int e = g[p];
    int rank = 0;
    for (int q = 0; q < NPAIR; ++q) rank += (q < p) && (g[q] == e);
    int slot = start[e] + rank;
    wsi[64 + slot] = p;      // spair
    wsi[200 + p] = slot;     // slot_of_pair

    if (p == 0) {
        int t = 0;
        for (int e2 = 0; e2 < EE; ++e2) {
            for (int o = 0; o < cnt[e2]; o += 4) {
                wsi[128 + t] = e2;
                wsi[152 + t] = start[e2] + o;
                wsi[176 + t] = (cnt[e2] - o) < 4 ? (cnt[e2] - o) : 4;
                ++t;
            }
        }
        for (; t < MAXT; ++t) wsi[176 + t] = 0;
    }
}

// ---------------------------------------------------------------------------
// x -> bf16 pack (once): 786432 elems, 8/thread
__global__ __launch_bounds__(256) void pack_x(
    const float* __restrict__ x, unsigned short* __restrict__ xbf)
{
    int i = blockIdx.x * 256 + threadIdx.x;   // 384 blocks
    const float4* src = (const float4*)(x + (size_t)i * 8);
    float4 v0 = src[0], v1 = src[1];
    us8 u;
    u[0] = f2bf(v0.x); u[1] = f2bf(v0.y); u[2] = f2bf(v0.z); u[3] = f2bf(v0.w);
    u[4] = f2bf(v1.x); u[5] = f2bf(v1.y); u[6] = f2bf(v1.z); u[7] = f2bf(v1.w);
    *(us8*)(xbf + (size_t)i * 8) = u;
}

// ---------------------------------------------------------------------------
// Fallback init: out = bias sums (down<1> atomics add on top)
__global__ __launch_bounds__(256) void init_kernel(
    const int* __restrict__ gates, const float* __restrict__ b2,
    float* __restrict__ out)
{
    int idx = blockIdx.x * 256 + threadIdx.x;
    if (idx >= BB * SS * DD) return;
    int b = idx / (SS * DD);
    int d = idx % DD;
    int e0 = gates[b * KK + 0];
    int e1 = gates[b * KK + 1];
    out[idx] = b2[e0 * DD + d] + b2[e1 * DD + d];
}

// ---------------------------------------------------------------------------
// Up GEMM (R14/R15 version): BM=128 BN=128 BK=64, 4 waves 2x2 (wave 64x64),
// dual reg sets, issue-before-store, NO-DRAIN barriers, 1D grid XCD decode
// (24 nt-groups = 3 balanced XCD rounds). gridDim = 8*MAXT*3 = 528.
__global__ __launch_bounds__(256, 2) void up_gemm(
    const unsigned short* __restrict__ xbf, const float* __restrict__ W1,
    const float* __restrict__ b1, const int* __restrict__ wsi,
    unsigned short* __restrict__ H)
{
    int bid = blockIdx.x;
    int xcd = bid & 7;
    int r = bid >> 3;
    int tile = r % MAXT;
    int grp = r / MAXT;          // 0..2
    int nt = grp * 8 + xcd;      // 0..23
    int np = wsi[176 + tile];
    if (np == 0) return;
    int e = wsi[128 + tile];
    int slot0 = wsi[152 + tile];
    int tid = threadIdx.x;
    int wid = tid >> 6, lane = tid & 63;
    int wm = wid >> 1, wn = wid & 1;

    __shared__ char lds[65536];

    const unsigned short* asrc[4];
    int aoff[4];
#pragma unroll
    for (int i = 0; i < 4; ++i) {
        int c = tid + i * 256;
        int row = c >> 3, ch = c & 7;
        int lp = row >> 5;
        int lpc = lp < np ? lp : np - 1;
        int pair = wsi[64 + slot0 + lpc];
        int b = pair >> 1;
        asrc[i] = xbf + ((size_t)(b * SS + (row & 31))) * DD + ch * 8;
        aoff[i] = lds_off(row, ch * 16);
    }
    int n = tid & 127, kq = tid >> 7;
    const float* bsrc = W1 + ((size_t)e * DD + kq * 32) * FFD + nt * 128 + n;
    int boff[4];
#pragma unroll
    for (int m4 = 0; m4 < 4; ++m4) boff[m4] = lds_off(n, kq * 64 + m4 * 16);

    f32x4 acc[4][4];
#pragma unroll
    for (int i = 0; i < 4; ++i)
#pragma unroll
        for (int j = 0; j < 4; ++j) acc[i][j] = (f32x4)0.f;

    float bB0[32], bB1[32];
    us8 bA0[4], bA1[4];

    auto issue = [&](int k0, float (&bB)[32], us8 (&bA)[4]) {
        const float* wp = bsrc + (size_t)k0 * FFD;
#pragma unroll
        for (int j = 0; j < 32; ++j) bB[j] = wp[(size_t)j * FFD];
#pragma unroll
        for (int i = 0; i < 4; ++i) bA[i] = *(const us8*)(asrc[i] + k0);
    };
    auto store = [&](int p, const float (&bB)[32], const us8 (&bA)[4]) {
        char* Al = lds + p * 32768;
        char* Bl = Al + 16384;
#pragma unroll
        for (int i = 0; i < 4; ++i) *(us8*)(Al + aoff[i]) = bA[i];
#pragma unroll
        for (int m4 = 0; m4 < 4; ++m4) {
            us8 u;
#pragma unroll
            for (int m = 0; m < 8; ++m) u[m] = f2bf(bB[m4 * 8 + m]);
            *(us8*)(Bl + boff[m4]) = u;
        }
    };
    auto compute = [&](int p) {
        char* Al = lds + p * 32768;
        char* Bl = Al + 16384;
#pragma unroll
        for (int kk = 0; kk < 2; ++kk) {
            int kb = kk * 64 + (lane >> 4) * 16;
            short8 af[4], bf[4];
#pragma unroll
            for (int mf = 0; mf < 4; ++mf)
                af[mf] = *(short8*)(Al + lds_off(wm * 64 + mf * 16 + (lane & 15), kb));
#pragma unroll
            for (int nf = 0; nf < 4; ++nf)
                bf[nf] = *(short8*)(Bl + lds_off(wn * 64 + nf * 16 + (lane & 15), kb));
#pragma unroll
            for (int mf = 0; mf < 4; ++mf)
#pragma unroll
                for (int nf = 0; nf < 4; ++nf)
                    acc[mf][nf] = __builtin_amdgcn_mfma_f32_16x16x32_bf16(
                        af[mf], bf[nf], acc[mf][nf], 0, 0, 0);
        }
    };

    const int steps = 12;   // DD/64
    issue(0, bB0, bA0);
    issue(64, bB1, bA1);
    store(0, bB0, bA0);
    phase_barrier();
    for (int s = 0; s < steps; s += 2) {
        compute(0);
        if (s + 2 < steps) issue((s + 2) * 64, bB0, bA0);
        store(1, bB1, bA1);
        phase_barrier();
        compute(1);
        if (s + 2 < steps) {
            if (s + 3 < steps) issue((s + 3) * 64, bB1, bA1);
            store(0, bB0, bA0);
        }
        phase_barrier();
    }

    // epilogue: bias + exact gelu -> bf16 H (grouped slot rows)
    float bias[4];
#pragma unroll
    for (int nf = 0; nf < 4; ++nf)
        bias[nf] = b1[e * FFD + nt * 128 + wn * 64 + nf * 16 + (lane & 15)];
#pragma unroll
    for (int mf = 0; mf < 4; ++mf) {
#pragma unroll
        for (int i = 0; i < 4; ++i) {
            int row = wm * 64 + mf * 16 + (lane >> 4) * 4 + i;
            if ((row >> 5) >= np) continue;
            size_t srow = (size_t)(slot0 * 32 + row);
#pragma unroll
            for (int nf = 0; nf < 4; ++nf) {
                int f = nt * 128 + wn * 64 + nf * 16 + (lane & 15);
                float h = acc[mf][nf][i] + bias[nf];
                float g = 0.5f * h * (1.0f + erff(h * 0.70710678118654752f));
                H[srow * FFD + f] = f2bf(g);
            }
        }
    }
}

// ---------------------------------------------------------------------------
// Down GEMM: BM=128 BN=128 BK=64, z=4 (steps=12). Plain __syncthreads
// (no-drain hurt down, R15). BALANCED XCD pinning: 24 (nt,z) panel-groups =
// 3 rounds of 8 XCDs (R14's failure was 12 unbalanced groups). Same-expert
// tiles of one group hit the same XCD L2 (W2 slice 393KB/expert).
// gridDim = 8 * MAXT * 3; pairidx = grp*8+xcd in 0..23; nt=pairidx%6,
// z=pairidx/6. MODE 0: bf16 partials; MODE 1: atomic fallback.
template<int MODE>
__global__ __launch_bounds__(256, 2) void down_gemm(
    const unsigned short* __restrict__ H, const float* __restrict__ W2,
    const int* __restrict__ wsi, unsigned short* __restrict__ part,
    float* __restrict__ out)
{
    int bid = blockIdx.x;
    int xcd = bid & 7;
    int r = bid >> 3;
    int tile = r % MAXT;
    int grp = r / MAXT;              // 0..2
    int pairidx = grp * 8 + xcd;     // 0..23, all real
    int nt = pairidx % 6;
    int z = pairidx / 6;             // 0..3
    int np = wsi[176 + tile];
    if (np == 0) return;
    int e = wsi[128 + tile];
    int slot0 = wsi[152 + tile];
    int zb = z * (FFD / 4);
    int tid = threadIdx.x;
    int wid = tid >> 6, lane = tid & 63;
    int wm = wid >> 1, wn = wid & 1;

    __shared__ char lds[65536];

    const unsigned short* asrc[4];
    int aoff[4];
#pragma unroll
    for (int i = 0; i < 4; ++i) {
        int c = tid + i * 256;
        int row = c >> 3, ch = c & 7;
        int rc = row < np * 32 ? row : np * 32 - 1;
        asrc[i] = H + (size_t)(slot0 * 32 + rc) * FFD + zb + ch * 8;
        aoff[i] = lds_off(row, ch * 16);
    }
    int n = tid & 127, kq = tid >> 7;
    const float* bsrc = W2 + ((size_t)e * FFD + zb + kq * 32) * DD + nt * 128 + n;
    int boff[4];
#pragma unroll
    for (int m4 = 0; m4 < 4; ++m4) boff[m4] = lds_off(n, kq * 64 + m4 * 16);

    f32x4 acc[4][4];
#pragma unroll
    for (int i = 0; i < 4; ++i)
#pragma unroll
        for (int j = 0; j < 4; ++j) acc[i][j] = (f32x4)0.f;

    float bB0[32], bB1[32];
    us8 bA0[4], bA1[4];

    auto issue = [&](int k0, float (&bB)[32], us8 (&bA)[4]) {
        const float* wp = bsrc + (size_t)k0 * DD;
#pragma unroll
        for (int j = 0; j < 32; ++j) bB[j] = wp[(size_t)j * DD];
#pragma unroll
        for (int i = 0; i < 4; ++i) bA[i] = *(const us8*)(asrc[i] + k0);
    };
    auto store = [&](int p, const float (&bB)[32], const us8 (&bA)[4]) {
        char* Al = lds + p * 32768;
        char* Bl = Al + 16384;
#pragma unroll
        for (int i = 0; i < 4; ++i) *(us8*)(Al + aoff[i]) = bA[i];
#pragma unroll
        for (int m4 = 0; m4 < 4; ++m4) {
            us8 u;
#pragma unroll
            for (int m = 0; m < 8; ++m) u[m] = f2bf(bB[m4 * 8 + m]);
            *(us8*)(Bl + boff[m4]) = u;
        }
    };
    auto compute = [&](int p) {
        char* Al = lds + p * 32768;
        char* Bl = Al + 16384;
#pragma unroll
        for (int kk = 0; kk < 2; ++kk) {
            int kb = kk * 64 + (lane >> 4) * 16;
            short8 af[4], bf[4];
#pragma unroll
            for (int mf = 0; mf < 4; ++mf)
                af[mf] = *(short8*)(Al + lds_off(wm * 64 + mf * 16 + (lane & 15), kb));
#pragma unroll
            for (int nf = 0; nf < 4; ++nf)
                bf[nf] = *(short8*)(Bl + lds_off(wn * 64 + nf * 16 + (lane & 15), kb));
#pragma unroll
            for (int mf = 0; mf < 4; ++mf)
#pragma unroll
                for (int nf = 0; nf < 4; ++nf)
                    acc[mf][nf] = __builtin_amdgcn_mfma_f32_16x16x32_bf16(
                        af[mf], bf[nf], acc[mf][nf], 0, 0, 0);
        }
    };

    const int steps = 12;   // (FFD/4)/64
    issue(0, bB0, bA0);
    issue(64, bB1, bA1);
    store(0, bB0, bA0);
    __syncthreads();
    for (int s = 0; s < steps; s += 2) {
        compute(0);
        if (s + 2 < steps) issue((s + 2) * 64, bB0, bA0);
        store(1, bB1, bA1);
        __syncthreads();
        compute(1);
        if (s + 2 < steps) {
            if (s + 3 < steps) issue((s + 3) * 64, bB1, bA1);
            store(0, bB0, bA0);
        }
        __syncthreads();
    }

    // epilogue
#pragma unroll
    for (int mf = 0; mf < 4; ++mf) {
#pragma unroll
        for (int i = 0; i < 4; ++i) {
            int row = wm * 64 + mf * 16 + (lane >> 4) * 4 + i;
            int lp = row >> 5;
            if (lp >= np) continue;
            int col = nt * 128 + wn * 64 + (lane & 15);
            if (MODE == 0) {
                size_t srow = (size_t)(slot0 * 32 + row);
                unsigned short* pp = part + (size_t)z * PZ + srow * DD + col;
#pragma unroll
                for (int nf = 0; nf < 4; ++nf) pp[nf * 16] = f2bf(acc[mf][nf][i]);
            } else {
                int pair = wsi[64 + slot0 + lp];
                int b = pair >> 1;
                int sI = row & 31;
                float* op = out + ((size_t)(b * SS + sI)) * DD + col;
#pragma unroll
                for (int nf = 0; nf < 4; ++nf)
                    atomicAdd(op + nf * 16, acc[mf][nf][i]);
            }
        }
    }
}

// ---------------------------------------------------------------------------
// Reduce: out[b,s,d0..d0+7] = sum_{k,z} part[z][slot(b,k)*32+s][d] + biases
__global__ __launch_bounds__(512) void reduce_kernel(
    const unsigned short* __restrict__ part, const int* __restrict__ wsi,
    const float* __restrict__ b2, float* __restrict__ out)
{
    int i8 = blockIdx.x * 512 + threadIdx.x;    // 98304 threads, 8 elems each
    int flat = i8 * 8;
    int b = flat / (SS * DD);
    int r = flat - b * (SS * DD);
    int s = r / DD;
    int d = r - s * DD;

    int e0 = wsi[b * KK + 0];
    int e1 = wsi[b * KK + 1];
    int sl0 = wsi[200 + b * KK + 0];
    int sl1 = wsi[200 + b * KK + 1];
    size_t r0 = (size_t)(sl0 * 32 + s) * DD + d;
    size_t r1 = (size_t)(sl1 * 32 + s) * DD + d;

    const float* bb0 = b2 + e0 * DD + d;
    const float* bb1 = b2 + e1 * DD + d;

    float v[8];
#pragma unroll
    for (int j = 0; j < 8; ++j) v[j] = bb0[j] + bb1[j];
#pragma unroll
    for (int z = 0; z < 4; ++z) {
        us8 p0 = *(const us8*)(part + (size_t)z * PZ + r0);
        us8 p1 = *(const us8*)(part + (size_t)z * PZ + r1);
#pragma unroll
        for (int j = 0; j < 8; ++j) v[j] += bf2f(p0[j]) + bf2f(p1[j]);
    }
    float4* op = (float4*)(out + flat);
    op[0] = make_float4(v[0], v[1], v[2], v[3]);
    op[1] = make_float4(v[4], v[5], v[6], v[7]);
}

// ---------------------------------------------------------------------------
extern "C" void kernel_launch(void* const* d_in, const int* in_sizes, int n_in,
                              void* d_out, int out_size, void* d_ws, size_t ws_size,
                              hipStream_t stream) {
    const float* x  = (const float*)d_in[0];
    const float* Wg = (const float*)d_in[2];
    const float* bg = (const float*)d_in[3];
    const float* W1 = (const float*)d_in[4];
    const float* b1 = (const float*)d_in[5];
    const float* W2 = (const float*)d_in[6];
    const float* b2 = (const float*)d_in[7];
    float* out = (float*)d_out;

    int* wsi = (int*)d_ws;
    unsigned short* H    = (unsigned short*)((char*)d_ws + H_OFF);
    unsigned short* xbf  = (unsigned short*)((char*)d_ws + XBF_OFF);
    unsigned short* part = (unsigned short*)((char*)d_ws + PART_OFF);
    // xbf/part overlay safe: pack_x -> up_gemm (reads xbf) -> down_gemm
    // (writes part) are stream-ordered.

    gate_kernel<<<BB, 256, 0, stream>>>(x, Wg, bg, out, wsi);
    sched_kernel<<<1, 64, 0, stream>>>(wsi);
    pack_x<<<(BB * SS * DD) / (256 * 8), 256, 0, stream>>>(x, xbf);
    up_gemm<<<8 * MAXT * 3, 256, 0, stream>>>(xbf, W1, b1, wsi, H);

    if (ws_size >= WS_MAIN) {
        down_gemm<0><<<8 * MAXT * 3, 256, 0, stream>>>(H, W2, wsi, part, out);
        reduce_kernel<<<(BB * SS * DD) / (512 * 8), 512, 0, stream>>>(
            part, wsi, b2, out);
    } else {
        init_kernel<<<(BB * SS * DD + 255) / 256, 256, 0, stream>>>(wsi, b2, out);
        down_gemm<1><<<8 * MAXT * 3, 256, 0, stream>>>(H, W2, wsi, part, out);
    }
}